// Round 9
// baseline (189.303 us; speedup 1.0000x reference)
//
#include <hip/hip_runtime.h>
#include <stdint.h>

#define TOKENS 16384
#define DDIM   1024
#define NEXP   64
#define NCOL   128              // 64 gate + 64 noise cols
#define TB     32               // tokens per block in K1
#define NBLK   (TOKENS / TB)    // 512 blocks
#define NCH    (DDIM / 32)      // 32 k-chunks of 32
#define NTILE  8                // 8 col-tiles of 16
#define NTG    (TOKENS / 16)    // 1024 token-groups of 16

typedef __attribute__((ext_vector_type(8))) short bf16x8;  // 8 bf16 = 4 VGPR
typedef __attribute__((ext_vector_type(4))) float f32x4;

// -------- device-global scratch --------
// W pre-split, fragment order: g_wf[p][ct][kc][lane][j] =
//   W_p[ct*16+(lane&15)][kc*32+(lane>>4)*8+j]        (768 KB, L2-resident)
__device__ ushort g_wf[3][NTILE][NCH][64][8];
// x pre-split, fragment order: g_xf[p][tg][kc][lane][j] =
//   x_p[tg*16+(lane&15)][kc*32+(lane>>4)*8+j]        (96 MB, L3-resident)
__device__ ushort g_xf[3][NTG][NCH][64][8];
__device__ float g_ps[NEXP];          // sum of clean router probs per expert
__device__ float g_cnt[NEXP];         // top-2 counts per expert
__device__ float g_spa[1];            // sum of softplus

// ---------------- bf16 3-way split (x = h + m + l + O(2^-27 x)) ----------------
__device__ inline ushort bf16rne(float f) {
  uint32_t u = __float_as_uint(f);
  return (ushort)((u + 0x7fffu + ((u >> 16) & 1u)) >> 16);
}
__device__ inline float bf16tof(ushort h) {
  return __uint_as_float(((uint32_t)h) << 16);
}
__device__ inline void split3(float v, ushort& h, ushort& m, ushort& l) {
  h = bf16rne(v);
  float r1 = v - bf16tof(h);     // exact
  m = bf16rne(r1);
  float r2 = r1 - bf16tof(m);    // exact
  l = bf16rne(r2);
}

// ---------------- JAX threefry2x32 (20 rounds) ----------------
struct U2 { uint32_t a, b; };

__host__ __device__ constexpr U2 tf2x32(uint32_t k0, uint32_t k1,
                                        uint32_t x0, uint32_t x1) {
  uint32_t ks[3] = {k0, k1, k0 ^ k1 ^ 0x1BD11BDAu};
  const uint32_t rot[2][4] = {{13u, 15u, 26u, 6u}, {17u, 29u, 16u, 24u}};
  x0 += ks[0]; x1 += ks[1];
  for (int d = 0; d < 5; ++d) {
    for (int j = 0; j < 4; ++j) {
      uint32_t r = rot[d & 1][j];
      x0 += x1;
      x1 = (x1 << r) | (x1 >> (32u - r));
      x1 ^= x0;
    }
    x0 += ks[(d + 1) % 3];
    x1 += ks[(d + 2) % 3] + (uint32_t)(d + 1);
  }
  return U2{x0, x1};
}

// JAX >=0.5 partitionable threefry: bits[i] = xor-fold(tf(key, (0, i)))
__device__ inline uint32_t noise_bits(uint32_t i) {
  constexpr U2 NK = tf2x32(0u, 0u, 0u, 12345u);   // fold_in(key(0), 12345)
  U2 o = tf2x32(NK.a, NK.b, 0u, i);
  return o.a ^ o.b;
}

// XLA ErfInv32 (Giles polynomial)
__device__ inline float xla_erfinv(float x) {
  float w = -log1pf(-x * x);
  float p;
  if (w < 5.0f) {
    w = w - 2.5f;
    p = 2.81022636e-08f;
    p = 3.43273939e-07f + p * w;
    p = -3.5233877e-06f + p * w;
    p = -4.39150654e-06f + p * w;
    p = 0.00021858087f + p * w;
    p = -0.00125372503f + p * w;
    p = -0.00417768164f + p * w;
    p = 0.246640727f + p * w;
    p = 1.50140941f + p * w;
  } else {
    w = sqrtf(w) - 3.0f;
    p = -0.000200214257f;
    p = 0.000100950558f + p * w;
    p = 0.00134934322f + p * w;
    p = -0.00367342844f + p * w;
    p = 0.00573950773f + p * w;
    p = -0.0076224613f + p * w;
    p = 0.00943887047f + p * w;
    p = 1.00167406f + p * w;
    p = 2.83297682f + p * w;
  }
  return p * x;
}

__device__ inline float noise_normal(uint32_t i) {
  uint32_t bits = noise_bits(i);
  float f = __uint_as_float((bits >> 9) | 0x3f800000u) - 1.0f;  // [0,1)
  float u = f * 2.0f + (-0.99999994f);
  u = fmaxf(u, -0.99999994f);
  return 1.41421356237f * xla_erfinv(u);
}

__device__ inline float softplus_ref(float x) {
  return fmaxf(x, 0.0f) + log1pf(expf(-fabsf(x)));
}

// ---------------- wave(64) primitives ----------------
__device__ inline float wave_max64(float v) {
  #pragma unroll
  for (int off = 32; off; off >>= 1) v = fmaxf(v, __shfl_xor(v, off, 64));
  return v;
}
__device__ inline float wave_sum64(float v) {
  #pragma unroll
  for (int off = 32; off; off >>= 1) v += __shfl_xor(v, off, 64);
  return v;
}
__device__ inline void wave_argmax64(float v, int idx, float& mv, int& mi) {
  float bv = v; int bi = idx;
  #pragma unroll
  for (int off = 32; off; off >>= 1) {
    float ov = __shfl_xor(bv, off, 64);
    int   oi = __shfl_xor(bi, off, 64);
    if (ov > bv || (ov == bv && oi < bi)) { bv = ov; bi = oi; }
  }
  mv = bv; mi = bi;
}

// ---------------- K0a: split W into fragment-ordered bf16 h/m/l ----------------
__global__ __launch_bounds__(64)
void wsplit_kernel(const float* __restrict__ wg, const float* __restrict__ wn) {
  const int ct   = blockIdx.x >> 5;      // col tile 0..7
  const int kc   = blockIdx.x & 31;      // k-chunk 0..31
  const int lane = threadIdx.x;          // 0..63
  const int col  = ct * 16 + (lane & 15);
  const int koff = kc * 32 + (lane >> 4) * 8;
  const float* src = (col < NEXP) ? (wg + (size_t)col * DDIM)
                                  : (wn + (size_t)(col - NEXP) * DDIM);
  const float4 v0 = *(const float4*)&src[koff];
  const float4 v1 = *(const float4*)&src[koff + 4];
  const float av[8] = {v0.x, v0.y, v0.z, v0.w, v1.x, v1.y, v1.z, v1.w};
  union BF8 { bf16x8 v; ushort u[8]; };
  BF8 H, M, L;
  #pragma unroll
  for (int j = 0; j < 8; ++j) {
    ushort h, m, l;
    split3(av[j], h, m, l);
    H.u[j] = h; M.u[j] = m; L.u[j] = l;
  }
  *(bf16x8*)&g_wf[0][ct][kc][lane][0] = H.v;
  *(bf16x8*)&g_wf[1][ct][kc][lane][0] = M.v;
  *(bf16x8*)&g_wf[2][ct][kc][lane][0] = L.v;

  if (blockIdx.x == 0) {   // zero loss accumulators (kernel boundary orders)
    g_ps[lane] = 0.0f; g_cnt[lane] = 0.0f;
    if (lane == 0) g_spa[0] = 0.0f;
  }
}

// ---------------- K0b: split x into fragment-ordered bf16 h/m/l ----------------
// grid = NTG*8 blocks x 256 threads (4 waves). Wave handles one (tg, kc):
// split3 once per element (K1 previously recomputed it 4x per chunk).
__global__ __launch_bounds__(256)
void xsplit_kernel(const float* __restrict__ x) {
  const int tg   = blockIdx.x >> 3;            // 0..1023
  const int kc   = (blockIdx.x & 7) * 4 + (threadIdx.x >> 6);   // 0..31
  const int lane = threadIdx.x & 63;
  const int row  = tg * 16 + (lane & 15);
  const int koff = kc * 32 + (lane >> 4) * 8;
  const float* src = x + (size_t)row * DDIM + koff;
  const float4 v0 = *(const float4*)&src[0];
  const float4 v1 = *(const float4*)&src[4];
  const float av[8] = {v0.x, v0.y, v0.z, v0.w, v1.x, v1.y, v1.z, v1.w};
  union BF8 { bf16x8 v; ushort u[8]; };
  BF8 H, M, L;
  #pragma unroll
  for (int j = 0; j < 8; ++j) {
    ushort h, m, l;
    split3(av[j], h, m, l);
    H.u[j] = h; M.u[j] = m; L.u[j] = l;
  }
  *(bf16x8*)&g_xf[0][tg][kc][lane][0] = H.v;
  *(bf16x8*)&g_xf[1][tg][kc][lane][0] = M.v;
  *(bf16x8*)&g_xf[2][tg][kc][lane][0] = L.v;
}

// ---------------- K1: barrier-free MFMA GEMM, all-coalesced, ping-pong ----------------
// block = 512 threads (8 waves) = 32 tokens x 128 cols x full K.
// waves: tg = w>>2 (16-token group), cg = w&3 (2 col-tiles).
// Inner loop: 9 coalesced 16B/lane loads (3 A + 6 B) + 12 MFMA, ZERO split
// VALU (operands pre-split by K0a/K0b). Explicit ping-pong double buffer:
// no register rotates, fully static indexing (rule #20).
// Same bf16 operands + same MFMA order as r5-r8 -> bit-identical output.
__global__ __launch_bounds__(512, 4)
void NoisyTopKRouter_57621281243491_kernel(float* __restrict__ out) {
  __shared__ float lds_logits[TB][NCOL + 4];   // 16.9 KB
  __shared__ float lps[8][NEXP];
  __shared__ float lcb[8][NEXP];
  __shared__ float lspw[8];

  const int tid  = threadIdx.x;
  const int w    = tid >> 6;          // wave 0..7
  const int lane = tid & 63;
  const int tg   = w >> 2;            // token group 0..1
  const int cg   = w & 3;             // col group 0..3
  const int tok0 = blockIdx.x * TB;

  const int fr_row = lane & 15;       // fragment row within 16
  const int fr_s   = lane >> 4;       // k-oct 0..3

  // A source: fragment-ordered x. strides (ushorts): product 16777216,
  // tg 16384, chunk 512.
  const ushort* xf = &g_xf[0][0][0][0][0];
  const int tgid = blockIdx.x * 2 + tg;
  const int a0 = tgid * 16384 + lane * 8;
  #define PX 16777216
  // B source: fragment-ordered W. strides (ushorts): product 131072,
  // tile 16384, chunk 512. Wave's tiles: cg*2, cg*2+1.
  const ushort* wf = &g_wf[0][0][0][0][0];
  const int b00 = (cg * 2) * 16384 + lane * 8;
  const int b10 = (cg * 2 + 1) * 16384 + lane * 8;
  #define PS 131072

  f32x4 acc0 = {0.f, 0.f, 0.f, 0.f};
  f32x4 acc1 = {0.f, 0.f, 0.f, 0.f};

  // ping-pong buffers (two full operand sets; static names, no rotates)
  bf16x8 Ah0, Am0, Al0, B0h0, B0m0, B0l0, B1h0, B1m0, B1l0;
  bf16x8 Ah1, Am1, Al1, B0h1, B0m1, B0l1, B1h1, B1m1, B1l1;

  #define LOADCH(kn, AH, AM, AL, C0H, C0M, C0L, C1H, C1M, C1L)          \
    { const int co_ = (kn) * 512;                                        \
      AH  = *(const bf16x8*)&xf[a0 + co_];                               \
      AM  = *(const bf16x8*)&xf[a0 + PX + co_];                          \
      AL  = *(const bf16x8*)&xf[a0 + 2 * PX + co_];                      \
      C0H = *(const bf16x8*)&wf[b00 + co_];                              \
      C0M = *(const bf16x8*)&wf[b00 + PS + co_];                         \
      C0L = *(const bf16x8*)&wf[b00 + 2 * PS + co_];                     \
      C1H = *(const bf16x8*)&wf[b10 + co_];                              \
      C1M = *(const bf16x8*)&wf[b10 + PS + co_];                         \
      C1L = *(const bf16x8*)&wf[b10 + 2 * PS + co_]; }

  #define MFMACH(AH, AM, AL, C0H, C0M, C0L, C1H, C1M, C1L)                     \
    acc0 = __builtin_amdgcn_mfma_f32_16x16x32_bf16(AH, C0H, acc0, 0, 0, 0);    \
    acc0 = __builtin_amdgcn_mfma_f32_16x16x32_bf16(AH, C0M, acc0, 0, 0, 0);    \
    acc0 = __builtin_amdgcn_mfma_f32_16x16x32_bf16(AM, C0H, acc0, 0, 0, 0);    \
    acc0 = __builtin_amdgcn_mfma_f32_16x16x32_bf16(AH, C0L, acc0, 0, 0, 0);    \
    acc0 = __builtin_amdgcn_mfma_f32_16x16x32_bf16(AL, C0H, acc0, 0, 0, 0);    \
    acc0 = __builtin_amdgcn_mfma_f32_16x16x32_bf16(AM, C0M, acc0, 0, 0, 0);    \
    acc1 = __builtin_amdgcn_mfma_f32_16x16x32_bf16(AH, C1H, acc1, 0, 0, 0);    \
    acc1 = __builtin_amdgcn_mfma_f32_16x16x32_bf16(AH, C1M, acc1, 0, 0, 0);    \
    acc1 = __builtin_amdgcn_mfma_f32_16x16x32_bf16(AM, C1H, acc1, 0, 0, 0);    \
    acc1 = __builtin_amdgcn_mfma_f32_16x16x32_bf16(AH, C1L, acc1, 0, 0, 0);    \
    acc1 = __builtin_amdgcn_mfma_f32_16x16x32_bf16(AL, C1H, acc1, 0, 0, 0);    \
    acc1 = __builtin_amdgcn_mfma_f32_16x16x32_bf16(AM, C1M, acc1, 0, 0, 0);

  // prologue: chunk 0 -> buffer 0
  LOADCH(0, Ah0, Am0, Al0, B0h0, B0m0, B0l0, B1h0, B1m0, B1l0);

  for (int i = 0; i < NCH / 2; ++i) {
    const int kc0 = 2 * i;
    // load chunk kc0+1 into buf1, compute chunk kc0 from buf0
    LOADCH(kc0 + 1, Ah1, Am1, Al1, B0h1, B0m1, B0l1, B1h1, B1m1, B1l1);
    MFMACH(Ah0, Am0, Al0, B0h0, B0m0, B0l0, B1h0, B1m0, B1l0);
    // load chunk kc0+2 (clamped on last) into buf0, compute kc0+1 from buf1
    const int kn = (kc0 + 2 < NCH) ? kc0 + 2 : NCH - 1;
    LOADCH(kn, Ah0, Am0, Al0, B0h0, B0m0, B0l0, B1h0, B1m0, B1l0);
    MFMACH(Ah1, Am1, Al1, B0h1, B0m1, B0l1, B1h1, B1m1, B1l1);
  }
  #undef LOADCH
  #undef MFMACH
  #undef PX
  #undef PS

  // C-write to LDS logits: D row = 4*(lane>>4)+reg, col = lane&15 (m89-verified)
  #pragma unroll
  for (int r = 0; r < 4; ++r) {
    lds_logits[tg * 16 + 4 * fr_s + r][cg * 32 + fr_row]      = acc0[r];
    lds_logits[tg * 16 + 4 * fr_s + r][cg * 32 + 16 + fr_row] = acc1[r];
  }
  __syncthreads();   // the only block-wide barrier before the epilogue

  // ---- epilogue: 4 tokens per wave, lane = expert (identical to r1 K2 math) ----
  float* out_rw  = out;                        // [16384][2]
  float* out_idx = out + 2 * TOKENS;           // [16384][2]
  float* out_rp  = out + 4 * TOKENS + 1;       // [16384][64]

  float ps_acc = 0.0f, sp_acc = 0.0f, c_acc = 0.0f;

  for (int it = 0; it < 4; ++it) {
    const int tl = w * 4 + it;
    const int t  = tok0 + tl;
    const float cl = lds_logits[tl][lane];
    const float nl = lds_logits[tl][NEXP + lane];

    // router_probs = softmax(clean)
    const float m  = wave_max64(cl);
    const float v  = expf(cl - m);
    const float Z  = wave_sum64(v);
    const float rp = v / Z;
    out_rp[(size_t)t * NEXP + lane] = rp;
    ps_acc += rp;

    // noisy logits
    const float ns  = softplus_ref(nl);
    sp_acc += ns;
    const float noi = noise_normal((uint32_t)(t * NEXP + lane));
    const float lgn = __fadd_rn(cl, __fmul_rn(noi, ns));

    const float m2 = wave_max64(lgn);
    const float v2 = expf(lgn - m2);
    const float Z2 = wave_sum64(v2);
    const float p  = v2 / Z2;

    float p1; int i1;
    wave_argmax64(p, lane, p1, i1);
    const float pm = (lane == i1) ? -3.402823466e38f : p;
    float p2; int i2;
    wave_argmax64(pm, lane, p2, i2);

    c_acc += (float)((lane == i1) + (lane == i2));

    if (lane == 0) {
      const float s = p1 + p2;
      out_rw[t * 2 + 0]  = p1 / s;
      out_rw[t * 2 + 1]  = p2 / s;
      out_idx[t * 2 + 0] = (float)i1;
      out_idx[t * 2 + 1] = (float)i2;
    }
  }

  // block-level reduce, then one atomicAdd set per block
  lps[w][lane] = ps_acc;
  lcb[w][lane] = c_acc;
  const float spw = wave_sum64(sp_acc);
  if (lane == 0) lspw[w] = spw;
  __syncthreads();
  if (tid < NEXP) {
    float a = 0.0f, b = 0.0f;
    #pragma unroll
    for (int j = 0; j < 8; ++j) { a += lps[j][tid]; b += lcb[j][tid]; }
    atomicAdd(&g_ps[tid],  a);
    atomicAdd(&g_cnt[tid], b);
  }
  if (tid == 0) {
    float s = 0.0f;
    #pragma unroll
    for (int j = 0; j < 8; ++j) s += lspw[j];
    atomicAdd(&g_spa[0], s);
  }
}

// ---------------- K3: finalize scalars ----------------
__global__ void finalize_kernel(float* __restrict__ out) {
  const int lane = threadIdx.x;
  float term = (g_cnt[lane] / (float)TOKENS) * (g_ps[lane] / (float)TOKENS);
  #pragma unroll
  for (int off = 32; off; off >>= 1) term += __shfl_xor(term, off, 64);
  if (lane == 0) {
    out[4 * TOKENS] = 0.64f * term;   // LOAD_BALANCE_WEIGHT * NUM_EXPERTS
    out[4 * TOKENS + 1 + TOKENS * NEXP] = g_spa[0] / (float)(TOKENS * NEXP);
  }
}

// ---------------- host ----------------
extern "C" void kernel_launch(void* const* d_in, const int* in_sizes, int n_in,
                              void* d_out, int out_size, void* d_ws, size_t ws_size,
                              hipStream_t stream) {
  const float* x  = (const float*)d_in[0];   // f32 [4,4096,1024]
  const float* wg = (const float*)d_in[1];   // f32 [64,1024]
  const float* wn = (const float*)d_in[2];   // f32 [64,1024]
  float* out = (float*)d_out;                // f32, 1114114 elements

  (void)d_ws; (void)ws_size; (void)in_sizes; (void)n_in; (void)out_size;

  wsplit_kernel<<<NTILE * NCH, 64, 0, stream>>>(wg, wn);
  xsplit_kernel<<<NTG * 8, 256, 0, stream>>>(x);
  NoisyTopKRouter_57621281243491_kernel<<<NBLK, 512, 0, stream>>>(out);
  finalize_kernel<<<1, 64, 0, stream>>>(out);
}

// Round 10
// 144.627 us; speedup vs baseline: 1.3089x; 1.3089x over previous
//
#include <hip/hip_runtime.h>
#include <stdint.h>

#define TOKENS 16384
#define DDIM   1024
#define NEXP   64
#define NCOL   128              // 64 gate + 64 noise cols
#define TB     32               // tokens per block
#define NBLK   (TOKENS / TB)    // 512 blocks
#define NCH    (DDIM / 32)      // 32 k-chunks of 32
#define NTILE  8                // 8 col-tiles of 16
#define CPP    8                // chunks per K-phase (4 phases x 256 k)

typedef __attribute__((ext_vector_type(8))) short bf16x8;  // 8 bf16 = 4 VGPR
typedef __attribute__((ext_vector_type(4))) float f32x4;

// -------- device-global scratch --------
// W pre-split, fragment order: g_wf[p][ct][kc][lane][j] =
//   W_p[ct*16+(lane&15)][kc*32+(lane>>4)*8+j]        (768 KB, L2-resident)
__device__ ushort g_wf[3][NTILE][NCH][64][8];
__device__ float g_ps[NEXP];          // sum of clean router probs per expert
__device__ float g_cnt[NEXP];         // top-2 counts per expert
__device__ float g_spa[1];            // sum of softplus

// ---------------- bf16 3-way split (x = h + m + l + O(2^-27 x)) ----------------
__device__ inline ushort bf16rne(float f) {
  uint32_t u = __float_as_uint(f);
  return (ushort)((u + 0x7fffu + ((u >> 16) & 1u)) >> 16);
}
__device__ inline float bf16tof(ushort h) {
  return __uint_as_float(((uint32_t)h) << 16);
}
__device__ inline void split3(float v, ushort& h, ushort& m, ushort& l) {
  h = bf16rne(v);
  float r1 = v - bf16tof(h);     // exact
  m = bf16rne(r1);
  float r2 = r1 - bf16tof(m);    // exact
  l = bf16rne(r2);
}

// ---------------- JAX threefry2x32 (20 rounds) ----------------
struct U2 { uint32_t a, b; };

__host__ __device__ constexpr U2 tf2x32(uint32_t k0, uint32_t k1,
                                        uint32_t x0, uint32_t x1) {
  uint32_t ks[3] = {k0, k1, k0 ^ k1 ^ 0x1BD11BDAu};
  const uint32_t rot[2][4] = {{13u, 15u, 26u, 6u}, {17u, 29u, 16u, 24u}};
  x0 += ks[0]; x1 += ks[1];
  for (int d = 0; d < 5; ++d) {
    for (int j = 0; j < 4; ++j) {
      uint32_t r = rot[d & 1][j];
      x0 += x1;
      x1 = (x1 << r) | (x1 >> (32u - r));
      x1 ^= x0;
    }
    x0 += ks[(d + 1) % 3];
    x1 += ks[(d + 2) % 3] + (uint32_t)(d + 1);
  }
  return U2{x0, x1};
}

// JAX >=0.5 partitionable threefry: bits[i] = xor-fold(tf(key, (0, i)))
__device__ inline uint32_t noise_bits(uint32_t i) {
  constexpr U2 NK = tf2x32(0u, 0u, 0u, 12345u);   // fold_in(key(0), 12345)
  U2 o = tf2x32(NK.a, NK.b, 0u, i);
  return o.a ^ o.b;
}

// XLA ErfInv32 (Giles polynomial)
__device__ inline float xla_erfinv(float x) {
  float w = -log1pf(-x * x);
  float p;
  if (w < 5.0f) {
    w = w - 2.5f;
    p = 2.81022636e-08f;
    p = 3.43273939e-07f + p * w;
    p = -3.5233877e-06f + p * w;
    p = -4.39150654e-06f + p * w;
    p = 0.00021858087f + p * w;
    p = -0.00125372503f + p * w;
    p = -0.00417768164f + p * w;
    p = 0.246640727f + p * w;
    p = 1.50140941f + p * w;
  } else {
    w = sqrtf(w) - 3.0f;
    p = -0.000200214257f;
    p = 0.000100950558f + p * w;
    p = 0.00134934322f + p * w;
    p = -0.00367342844f + p * w;
    p = 0.00573950773f + p * w;
    p = -0.0076224613f + p * w;
    p = 0.00943887047f + p * w;
    p = 1.00167406f + p * w;
    p = 2.83297682f + p * w;
  }
  return p * x;
}

__device__ inline float noise_normal(uint32_t i) {
  uint32_t bits = noise_bits(i);
  float f = __uint_as_float((bits >> 9) | 0x3f800000u) - 1.0f;  // [0,1)
  float u = f * 2.0f + (-0.99999994f);
  u = fmaxf(u, -0.99999994f);
  return 1.41421356237f * xla_erfinv(u);
}

__device__ inline float softplus_ref(float x) {
  return fmaxf(x, 0.0f) + log1pf(expf(-fabsf(x)));
}

// ---------------- wave(64) primitives ----------------
__device__ inline float wave_max64(float v) {
  #pragma unroll
  for (int off = 32; off; off >>= 1) v = fmaxf(v, __shfl_xor(v, off, 64));
  return v;
}
__device__ inline float wave_sum64(float v) {
  #pragma unroll
  for (int off = 32; off; off >>= 1) v += __shfl_xor(v, off, 64);
  return v;
}
__device__ inline void wave_argmax64(float v, int idx, float& mv, int& mi) {
  float bv = v; int bi = idx;
  #pragma unroll
  for (int off = 32; off; off >>= 1) {
    float ov = __shfl_xor(bv, off, 64);
    int   oi = __shfl_xor(bi, off, 64);
    if (ov > bv || (ov == bv && oi < bi)) { bv = ov; bi = oi; }
  }
  mv = bv; mi = bi;
}

// ---------------- K0: split W into fragment-ordered bf16 h/m/l ----------------
__global__ __launch_bounds__(64)
void wsplit_kernel(const float* __restrict__ wg, const float* __restrict__ wn) {
  const int ct   = blockIdx.x >> 5;      // col tile 0..7
  const int kc   = blockIdx.x & 31;      // k-chunk 0..31
  const int lane = threadIdx.x;          // 0..63
  const int col  = ct * 16 + (lane & 15);
  const int koff = kc * 32 + (lane >> 4) * 8;
  const float* src = (col < NEXP) ? (wg + (size_t)col * DDIM)
                                  : (wn + (size_t)(col - NEXP) * DDIM);
  const float4 v0 = *(const float4*)&src[koff];
  const float4 v1 = *(const float4*)&src[koff + 4];
  const float av[8] = {v0.x, v0.y, v0.z, v0.w, v1.x, v1.y, v1.z, v1.w};
  union BF8 { bf16x8 v; ushort u[8]; };
  BF8 H, M, L;
  #pragma unroll
  for (int j = 0; j < 8; ++j) {
    ushort h, m, l;
    split3(av[j], h, m, l);
    H.u[j] = h; M.u[j] = m; L.u[j] = l;
  }
  *(bf16x8*)&g_wf[0][ct][kc][lane][0] = H.v;
  *(bf16x8*)&g_wf[1][ct][kc][lane][0] = M.v;
  *(bf16x8*)&g_wf[2][ct][kc][lane][0] = L.v;

  if (blockIdx.x == 0) {   // zero loss accumulators (kernel boundary orders)
    g_ps[lane] = 0.0f; g_cnt[lane] = 0.0f;
    if (lane == 0) g_spa[0] = 0.0f;
  }
}

// ---------------- K1: fused in-block x-split + MFMA GEMM + epilogue ----------------
// block = 512 threads (8 waves), TB=32 tokens x 128 cols x full K.
// K processed in 4 phases of 256: each phase {cooperative x-split (coalesced
// fp32 read, split3 ONCE per element, fragment-ordered LDS write) -> barrier
// -> 8 chunks of MFMA (A from LDS lane*16 conflict-free b128; B coalesced
// from L2-resident g_wf) -> barrier}. Next phase's x prefetched into regs
// before the barrier. Wave = one col-tile (ct=w), BOTH token groups ->
// B traffic halved vs r9 (393 MB total, ~11 us L2 floor).
// Same split3 inputs + same per-accumulator product/k order as r5-r9
// -> bit-identical logits.
__global__ __launch_bounds__(512, 4)
void NoisyTopKRouter_57621281243491_kernel(
    const float* __restrict__ x, float* __restrict__ out) {
  __shared__ ushort ldsA[3][2][CPP][64][8];     // 48 KB fragment-ordered x phase
  __shared__ float lds_logits[TB][NCOL + 4];    // 16.9 KB
  __shared__ float lps[8][NEXP];
  __shared__ float lcb[8][NEXP];
  __shared__ float lspw[8];

  const int tid  = threadIdx.x;
  const int w    = tid >> 6;          // wave 0..7 = col tile
  const int lane = tid & 63;
  const int tok0 = blockIdx.x * TB;

  // ---- split-phase role: coalesced x read, fragment-ordered LDS write ----
  const int srow = tid >> 4;          // 0..31 token row
  const int skq  = tid & 15;          // 0..15 (16 k each)
  const int stg  = srow >> 4;         // token group
  const int sfr  = srow & 15;         // fragment row
  const int sc   = skq >> 1;          // chunk within phase
  const int sl0  = ((skq & 1) * 2) * 16 + sfr;       // lane for k-oct s0
  const int sl1  = ((skq & 1) * 2 + 1) * 16 + sfr;   // lane for k-oct s0+1
  const float* sx = x + (size_t)(tok0 + srow) * DDIM + skq * 16;

  // ---- MFMA role ----
  const int fr_row = lane & 15;
  const int fr_s   = lane >> 4;
  const ushort* wf = &g_wf[0][0][0][0][0];
  const int b0 = w * 16384 + lane * 8;   // wave's col-tile, product h
  #define PS 131072

  f32x4 acc0 = {0.f, 0.f, 0.f, 0.f};    // token group 0
  f32x4 acc1 = {0.f, 0.f, 0.f, 0.f};    // token group 1

  float4 xrA[4], xrB[4];

  #define SPLIT_PHASE(XR)                                                 \
    {                                                                     \
      union BF8 { bf16x8 v; ushort u[8]; };                               \
      BF8 H0, M0, L0, H1, M1, L1;                                         \
      const float a0v[8] = {XR[0].x, XR[0].y, XR[0].z, XR[0].w,           \
                            XR[1].x, XR[1].y, XR[1].z, XR[1].w};          \
      const float a1v[8] = {XR[2].x, XR[2].y, XR[2].z, XR[2].w,           \
                            XR[3].x, XR[3].y, XR[3].z, XR[3].w};          \
      _Pragma("unroll")                                                   \
      for (int j = 0; j < 8; ++j) {                                       \
        ushort h, m, l;                                                   \
        split3(a0v[j], h, m, l);                                          \
        H0.u[j] = h; M0.u[j] = m; L0.u[j] = l;                            \
        split3(a1v[j], h, m, l);                                          \
        H1.u[j] = h; M1.u[j] = m; L1.u[j] = l;                            \
      }                                                                   \
      *(bf16x8*)&ldsA[0][stg][sc][sl0][0] = H0.v;                         \
      *(bf16x8*)&ldsA[1][stg][sc][sl0][0] = M0.v;                         \
      *(bf16x8*)&ldsA[2][stg][sc][sl0][0] = L0.v;                         \
      *(bf16x8*)&ldsA[0][stg][sc][sl1][0] = H1.v;                         \
      *(bf16x8*)&ldsA[1][stg][sc][sl1][0] = M1.v;                         \
      *(bf16x8*)&ldsA[2][stg][sc][sl1][0] = L1.v;                         \
    }

  #define MFMA_PHASE(ph)                                                  \
    _Pragma("unroll 2")                                                   \
    for (int c = 0; c < CPP; ++c) {                                       \
      const bf16x8 Ah0 = *(const bf16x8*)&ldsA[0][0][c][lane][0];         \
      const bf16x8 Am0 = *(const bf16x8*)&ldsA[1][0][c][lane][0];         \
      const bf16x8 Al0 = *(const bf16x8*)&ldsA[2][0][c][lane][0];         \
      const bf16x8 Ah1 = *(const bf16x8*)&ldsA[0][1][c][lane][0];         \
      const bf16x8 Am1 = *(const bf16x8*)&ldsA[1][1][c][lane][0];         \
      const bf16x8 Al1 = *(const bf16x8*)&ldsA[2][1][c][lane][0];         \
      const int co = ((ph) * CPP + c) * 512;                              \
      const bf16x8 Bh = *(const bf16x8*)&wf[b0 + co];                     \
      const bf16x8 Bm = *(const bf16x8*)&wf[b0 + PS + co];                \
      const bf16x8 Bl = *(const bf16x8*)&wf[b0 + 2 * PS + co];            \
      acc0 = __builtin_amdgcn_mfma_f32_16x16x32_bf16(Ah0, Bh, acc0, 0, 0, 0); \
      acc0 = __builtin_amdgcn_mfma_f32_16x16x32_bf16(Ah0, Bm, acc0, 0, 0, 0); \
      acc0 = __builtin_amdgcn_mfma_f32_16x16x32_bf16(Am0, Bh, acc0, 0, 0, 0); \
      acc0 = __builtin_amdgcn_mfma_f32_16x16x32_bf16(Ah0, Bl, acc0, 0, 0, 0); \
      acc0 = __builtin_amdgcn_mfma_f32_16x16x32_bf16(Al0, Bh, acc0, 0, 0, 0); \
      acc0 = __builtin_amdgcn_mfma_f32_16x16x32_bf16(Am0, Bm, acc0, 0, 0, 0); \
      acc1 = __builtin_amdgcn_mfma_f32_16x16x32_bf16(Ah1, Bh, acc1, 0, 0, 0); \
      acc1 = __builtin_amdgcn_mfma_f32_16x16x32_bf16(Ah1, Bm, acc1, 0, 0, 0); \
      acc1 = __builtin_amdgcn_mfma_f32_16x16x32_bf16(Am1, Bh, acc1, 0, 0, 0); \
      acc1 = __builtin_amdgcn_mfma_f32_16x16x32_bf16(Ah1, Bl, acc1, 0, 0, 0); \
      acc1 = __builtin_amdgcn_mfma_f32_16x16x32_bf16(Al1, Bh, acc1, 0, 0, 0); \
      acc1 = __builtin_amdgcn_mfma_f32_16x16x32_bf16(Am1, Bm, acc1, 0, 0, 0); \
    }

  // prologue: phase-0 x into regs
  #pragma unroll
  for (int q = 0; q < 4; ++q) xrA[q] = *(const float4*)&sx[q * 4];

  // phase 0
  SPLIT_PHASE(xrA);
  #pragma unroll
  for (int q = 0; q < 4; ++q) xrB[q] = *(const float4*)&sx[256 + q * 4];
  __syncthreads();
  MFMA_PHASE(0);
  __syncthreads();
  // phase 1
  SPLIT_PHASE(xrB);
  #pragma unroll
  for (int q = 0; q < 4; ++q) xrA[q] = *(const float4*)&sx[512 + q * 4];
  __syncthreads();
  MFMA_PHASE(1);
  __syncthreads();
  // phase 2
  SPLIT_PHASE(xrA);
  #pragma unroll
  for (int q = 0; q < 4; ++q) xrB[q] = *(const float4*)&sx[768 + q * 4];
  __syncthreads();
  MFMA_PHASE(2);
  __syncthreads();
  // phase 3
  SPLIT_PHASE(xrB);
  __syncthreads();
  MFMA_PHASE(3);

  #undef SPLIT_PHASE
  #undef MFMA_PHASE
  #undef PS

  // C-write: D row = 4*(lane>>4)+r, col = lane&15 (m89-verified); wave = ct
  #pragma unroll
  for (int r = 0; r < 4; ++r) {
    lds_logits[4 * fr_s + r][w * 16 + fr_row]      = acc0[r];   // tg0 rows 0..15
    lds_logits[16 + 4 * fr_s + r][w * 16 + fr_row] = acc1[r];   // tg1 rows 16..31
  }
  __syncthreads();

  // ---- epilogue: 4 tokens per wave, lane = expert (identical to r1 K2 math) ----
  float* out_rw  = out;                        // [16384][2]
  float* out_idx = out + 2 * TOKENS;           // [16384][2]
  float* out_rp  = out + 4 * TOKENS + 1;       // [16384][64]

  float ps_acc = 0.0f, sp_acc = 0.0f, c_acc = 0.0f;

  for (int it = 0; it < 4; ++it) {
    const int tl = w * 4 + it;
    const int t  = tok0 + tl;
    const float cl = lds_logits[tl][lane];
    const float nl = lds_logits[tl][NEXP + lane];

    // router_probs = softmax(clean)
    const float m  = wave_max64(cl);
    const float v  = expf(cl - m);
    const float Z  = wave_sum64(v);
    const float rp = v / Z;
    out_rp[(size_t)t * NEXP + lane] = rp;
    ps_acc += rp;

    // noisy logits
    const float ns  = softplus_ref(nl);
    sp_acc += ns;
    const float noi = noise_normal((uint32_t)(t * NEXP + lane));
    const float lgn = __fadd_rn(cl, __fmul_rn(noi, ns));

    const float m2 = wave_max64(lgn);
    const float v2 = expf(lgn - m2);
    const float Z2 = wave_sum64(v2);
    const float p  = v2 / Z2;

    float p1; int i1;
    wave_argmax64(p, lane, p1, i1);
    const float pm = (lane == i1) ? -3.402823466e38f : p;
    float p2; int i2;
    wave_argmax64(pm, lane, p2, i2);

    c_acc += (float)((lane == i1) + (lane == i2));

    if (lane == 0) {
      const float s = p1 + p2;
      out_rw[t * 2 + 0]  = p1 / s;
      out_rw[t * 2 + 1]  = p2 / s;
      out_idx[t * 2 + 0] = (float)i1;
      out_idx[t * 2 + 1] = (float)i2;
    }
  }

  // block-level reduce, then one atomicAdd set per block
  lps[w][lane] = ps_acc;
  lcb[w][lane] = c_acc;
  const float spw = wave_sum64(sp_acc);
  if (lane == 0) lspw[w] = spw;
  __syncthreads();
  if (tid < NEXP) {
    float a = 0.0f, b = 0.0f;
    #pragma unroll
    for (int j = 0; j < 8; ++j) { a += lps[j][tid]; b += lcb[j][tid]; }
    atomicAdd(&g_ps[tid],  a);
    atomicAdd(&g_cnt[tid], b);
  }
  if (tid == 0) {
    float s = 0.0f;
    #pragma unroll
    for (int j = 0; j < 8; ++j) s += lspw[j];
    atomicAdd(&g_spa[0], s);
  }
}

// ---------------- K3: finalize scalars ----------------
__global__ void finalize_kernel(float* __restrict__ out) {
  const int lane = threadIdx.x;
  float term = (g_cnt[lane] / (float)TOKENS) * (g_ps[lane] / (float)TOKENS);
  #pragma unroll
  for (int off = 32; off; off >>= 1) term += __shfl_xor(term, off, 64);
  if (lane == 0) {
    out[4 * TOKENS] = 0.64f * term;   // LOAD_BALANCE_WEIGHT * NUM_EXPERTS
    out[4 * TOKENS + 1 + TOKENS * NEXP] = g_spa[0] / (float)(TOKENS * NEXP);
  }
}

// ---------------- host ----------------
extern "C" void kernel_launch(void* const* d_in, const int* in_sizes, int n_in,
                              void* d_out, int out_size, void* d_ws, size_t ws_size,
                              hipStream_t stream) {
  const float* x  = (const float*)d_in[0];   // f32 [4,4096,1024]
  const float* wg = (const float*)d_in[1];   // f32 [64,1024]
  const float* wn = (const float*)d_in[2];   // f32 [64,1024]
  float* out = (float*)d_out;                // f32, 1114114 elements

  (void)d_ws; (void)ws_size; (void)in_sizes; (void)n_in; (void)out_size;

  wsplit_kernel<<<NTILE * NCH, 64, 0, stream>>>(wg, wn);
  NoisyTopKRouter_57621281243491_kernel<<<NBLK, 512, 0, stream>>>(x, out);
  finalize_kernel<<<1, 64, 0, stream>>>(out);
}

// Round 11
// 143.098 us; speedup vs baseline: 1.3229x; 1.0107x over previous
//
#include <hip/hip_runtime.h>
#include <stdint.h>

#define TOKENS 16384
#define DDIM   1024
#define NEXP   64
#define NCOL   128              // 64 gate + 64 noise cols
#define TB     32               // tokens per block
#define NBLK   (TOKENS / TB)    // 512 blocks
#define NCH    (DDIM / 32)      // 32 k-chunks of 32
#define NTILE  8                // 8 col-tiles of 16
#define CPP    4                // chunks per K-phase (8 phases x 128 k)

typedef __attribute__((ext_vector_type(8))) short bf16x8;  // 8 bf16 = 4 VGPR
typedef __attribute__((ext_vector_type(4))) float f32x4;

// -------- device-global scratch --------
// W pre-split, fragment order: g_wf[p][ct][kc][lane][j] =
//   W_p[ct*16+(lane&15)][kc*32+(lane>>4)*8+j]        (768 KB, L2-resident)
__device__ ushort g_wf[3][NTILE][NCH][64][8];
__device__ float g_ps[NEXP];          // sum of clean router probs per expert
__device__ float g_cnt[NEXP];         // top-2 counts per expert
__device__ float g_spa[1];            // sum of softplus

// ---------------- bf16 3-way split (x = h + m + l + O(2^-27 x)) ----------------
__device__ inline ushort bf16rne(float f) {
  uint32_t u = __float_as_uint(f);
  return (ushort)((u + 0x7fffu + ((u >> 16) & 1u)) >> 16);
}
__device__ inline float bf16tof(ushort h) {
  return __uint_as_float(((uint32_t)h) << 16);
}
__device__ inline void split3(float v, ushort& h, ushort& m, ushort& l) {
  h = bf16rne(v);
  float r1 = v - bf16tof(h);     // exact
  m = bf16rne(r1);
  float r2 = r1 - bf16tof(m);    // exact
  l = bf16rne(r2);
}

// ---------------- JAX threefry2x32 (20 rounds) ----------------
struct U2 { uint32_t a, b; };

__host__ __device__ constexpr U2 tf2x32(uint32_t k0, uint32_t k1,
                                        uint32_t x0, uint32_t x1) {
  uint32_t ks[3] = {k0, k1, k0 ^ k1 ^ 0x1BD11BDAu};
  const uint32_t rot[2][4] = {{13u, 15u, 26u, 6u}, {17u, 29u, 16u, 24u}};
  x0 += ks[0]; x1 += ks[1];
  for (int d = 0; d < 5; ++d) {
    for (int j = 0; j < 4; ++j) {
      uint32_t r = rot[d & 1][j];
      x0 += x1;
      x1 = (x1 << r) | (x1 >> (32u - r));
      x1 ^= x0;
    }
    x0 += ks[(d + 1) % 3];
    x1 += ks[(d + 2) % 3] + (uint32_t)(d + 1);
  }
  return U2{x0, x1};
}

// JAX >=0.5 partitionable threefry: bits[i] = xor-fold(tf(key, (0, i)))
__device__ inline uint32_t noise_bits(uint32_t i) {
  constexpr U2 NK = tf2x32(0u, 0u, 0u, 12345u);   // fold_in(key(0), 12345)
  U2 o = tf2x32(NK.a, NK.b, 0u, i);
  return o.a ^ o.b;
}

// XLA ErfInv32 (Giles polynomial)
__device__ inline float xla_erfinv(float x) {
  float w = -log1pf(-x * x);
  float p;
  if (w < 5.0f) {
    w = w - 2.5f;
    p = 2.81022636e-08f;
    p = 3.43273939e-07f + p * w;
    p = -3.5233877e-06f + p * w;
    p = -4.39150654e-06f + p * w;
    p = 0.00021858087f + p * w;
    p = -0.00125372503f + p * w;
    p = -0.00417768164f + p * w;
    p = 0.246640727f + p * w;
    p = 1.50140941f + p * w;
  } else {
    w = sqrtf(w) - 3.0f;
    p = -0.000200214257f;
    p = 0.000100950558f + p * w;
    p = 0.00134934322f + p * w;
    p = -0.00367342844f + p * w;
    p = 0.00573950773f + p * w;
    p = -0.0076224613f + p * w;
    p = 0.00943887047f + p * w;
    p = 1.00167406f + p * w;
    p = 2.83297682f + p * w;
  }
  return p * x;
}

__device__ inline float noise_normal(uint32_t i) {
  uint32_t bits = noise_bits(i);
  float f = __uint_as_float((bits >> 9) | 0x3f800000u) - 1.0f;  // [0,1)
  float u = f * 2.0f + (-0.99999994f);
  u = fmaxf(u, -0.99999994f);
  return 1.41421356237f * xla_erfinv(u);
}

__device__ inline float softplus_ref(float x) {
  return fmaxf(x, 0.0f) + log1pf(expf(-fabsf(x)));
}

// ---------------- wave(64) primitives ----------------
__device__ inline float wave_max64(float v) {
  #pragma unroll
  for (int off = 32; off; off >>= 1) v = fmaxf(v, __shfl_xor(v, off, 64));
  return v;
}
__device__ inline float wave_sum64(float v) {
  #pragma unroll
  for (int off = 32; off; off >>= 1) v += __shfl_xor(v, off, 64);
  return v;
}
__device__ inline void wave_argmax64(float v, int idx, float& mv, int& mi) {
  float bv = v; int bi = idx;
  #pragma unroll
  for (int off = 32; off; off >>= 1) {
    float ov = __shfl_xor(bv, off, 64);
    int   oi = __shfl_xor(bi, off, 64);
    if (ov > bv || (ov == bv && oi < bi)) { bv = ov; bi = oi; }
  }
  mv = bv; mi = bi;
}

// ---------------- K0: split W into fragment-ordered bf16 h/m/l ----------------
__global__ __launch_bounds__(64)
void wsplit_kernel(const float* __restrict__ wg, const float* __restrict__ wn) {
  const int ct   = blockIdx.x >> 5;      // col tile 0..7
  const int kc   = blockIdx.x & 31;      // k-chunk 0..31
  const int lane = threadIdx.x;          // 0..63
  const int col  = ct * 16 + (lane & 15);
  const int koff = kc * 32 + (lane >> 4) * 8;
  const float* src = (col < NEXP) ? (wg + (size_t)col * DDIM)
                                  : (wn + (size_t)(col - NEXP) * DDIM);
  const float4 v0 = *(const float4*)&src[koff];
  const float4 v1 = *(const float4*)&src[koff + 4];
  const float av[8] = {v0.x, v0.y, v0.z, v0.w, v1.x, v1.y, v1.z, v1.w};
  union BF8 { bf16x8 v; ushort u[8]; };
  BF8 H, M, L;
  #pragma unroll
  for (int j = 0; j < 8; ++j) {
    ushort h, m, l;
    split3(av[j], h, m, l);
    H.u[j] = h; M.u[j] = m; L.u[j] = l;
  }
  *(bf16x8*)&g_wf[0][ct][kc][lane][0] = H.v;
  *(bf16x8*)&g_wf[1][ct][kc][lane][0] = M.v;
  *(bf16x8*)&g_wf[2][ct][kc][lane][0] = L.v;

  if (blockIdx.x == 0) {   // zero loss accumulators (kernel boundary orders)
    g_ps[lane] = 0.0f; g_cnt[lane] = 0.0f;
    if (lane == 0) g_spa[0] = 0.0f;
  }
}

// ---------------- K1: fused in-block x-split + MFMA GEMM + epilogue ----------------
// block = 512 threads (8 waves), TB=32 tokens x 128 cols x full K.
// 8 K-phases of 128: {split x into swizzled fragment-ordered LDS (one bf16x8
// per thread per product) -> barrier -> 4 chunks MFMA (A from LDS swizzled
// b128; B coalesced from L2-resident g_wf) -> barrier}. Next phase's x
// prefetched into regs before the barrier.
// LDS = 24.6 KB only (epilogue logits/reduce buffers ALIAS the x-stage
// buffer; extra barrier after last MFMA protects overlap) -> 4 blocks/CU,
// 8 waves/SIMD (launch_bounds(512,8), r10 used 52 VGPR with more live regs).
// Store swizzle o^=((o>>8)&7)<<4 spreads fragment writes over all 8
// bank-quads (was 16-way conflicted); reads stay conflict-free.
// Same split3 inputs + same per-accumulator product/k order as r5-r10
// -> bit-identical logits.
__global__ __launch_bounds__(512, 8)
void NoisyTopKRouter_57621281243491_kernel(
    const float* __restrict__ x, float* __restrict__ out) {
  __shared__ ushort ldsA[3][2][CPP][64][8];     // 24.6 KB; epilogue aliases it

  const int tid  = threadIdx.x;
  const int w    = tid >> 6;          // wave 0..7 = col tile
  const int lane = tid & 63;
  const int tok0 = blockIdx.x * TB;

  char* LA = (char*)&ldsA[0][0][0][0][0];

  // ---- split-phase role: coalesced x read, swizzled fragment LDS write ----
  const int srow = tid >> 4;          // 0..31 token row
  const int skq  = tid & 15;          // 0..15: fragment (chunk, k-oct) in phase
  const int stg  = srow >> 4;         // token group
  const int sfr  = srow & 15;         // fragment row
  const int sc   = skq >> 2;          // chunk within phase
  const int ss   = skq & 3;           // k-oct within chunk
  // byte offset within a (product, tg) region, XOR-swizzled
  const int so   = (sc * 1024 + ss * 256 + sfr * 16) ^ ((skq & 7) << 4);
  const float* sx = x + (size_t)(tok0 + srow) * DDIM + skq * 8;

  // ---- MFMA role ----
  const int fr_row = lane & 15;
  const int fr_s   = lane >> 4;
  const ushort* wf = &g_wf[0][0][0][0][0];
  const int b0 = w * 16384 + lane * 8;   // wave's col-tile, product h
  #define PS 131072

  f32x4 acc0 = {0.f, 0.f, 0.f, 0.f};    // token group 0
  f32x4 acc1 = {0.f, 0.f, 0.f, 0.f};    // token group 1

  float4 xa0, xa1, xb0, xb1;

  #define SPLIT_PHASE(X0, X1)                                             \
    {                                                                     \
      union BF8 { bf16x8 v; ushort u[8]; };                               \
      BF8 H, M, L;                                                        \
      const float av_[8] = {X0.x, X0.y, X0.z, X0.w, X1.x, X1.y, X1.z, X1.w}; \
      _Pragma("unroll")                                                   \
      for (int j = 0; j < 8; ++j) {                                       \
        ushort h_, m_, l_;                                                \
        split3(av_[j], h_, m_, l_);                                       \
        H.u[j] = h_; M.u[j] = m_; L.u[j] = l_;                            \
      }                                                                   \
      *(bf16x8*)(LA + stg * 4096 + so)         = H.v;                     \
      *(bf16x8*)(LA + 8192 + stg * 4096 + so)  = M.v;                     \
      *(bf16x8*)(LA + 16384 + stg * 4096 + so) = L.v;                     \
    }

  #define MFMA_PHASE(ph)                                                  \
    _Pragma("unroll")                                                     \
    for (int c = 0; c < CPP; ++c) {                                       \
      int ro = c * 1024 + lane * 16;                                      \
      ro ^= ((ro >> 8) & 7) << 4;                                         \
      const bf16x8 Ah0 = *(const bf16x8*)(LA + ro);                       \
      const bf16x8 Am0 = *(const bf16x8*)(LA + 8192 + ro);                \
      const bf16x8 Al0 = *(const bf16x8*)(LA + 16384 + ro);               \
      const bf16x8 Ah1 = *(const bf16x8*)(LA + 4096 + ro);                \
      const bf16x8 Am1 = *(const bf16x8*)(LA + 12288 + ro);               \
      const bf16x8 Al1 = *(const bf16x8*)(LA + 20480 + ro);               \
      const int co = ((ph) * CPP + c) * 512;                              \
      const bf16x8 Bh = *(const bf16x8*)&wf[b0 + co];                     \
      const bf16x8 Bm = *(const bf16x8*)&wf[b0 + PS + co];                \
      const bf16x8 Bl = *(const bf16x8*)&wf[b0 + 2 * PS + co];            \
      acc0 = __builtin_amdgcn_mfma_f32_16x16x32_bf16(Ah0, Bh, acc0, 0, 0, 0); \
      acc0 = __builtin_amdgcn_mfma_f32_16x16x32_bf16(Ah0, Bm, acc0, 0, 0, 0); \
      acc0 = __builtin_amdgcn_mfma_f32_16x16x32_bf16(Am0, Bh, acc0, 0, 0, 0); \
      acc0 = __builtin_amdgcn_mfma_f32_16x16x32_bf16(Ah0, Bl, acc0, 0, 0, 0); \
      acc0 = __builtin_amdgcn_mfma_f32_16x16x32_bf16(Al0, Bh, acc0, 0, 0, 0); \
      acc0 = __builtin_amdgcn_mfma_f32_16x16x32_bf16(Am0, Bm, acc0, 0, 0, 0); \
      acc1 = __builtin_amdgcn_mfma_f32_16x16x32_bf16(Ah1, Bh, acc1, 0, 0, 0); \
      acc1 = __builtin_amdgcn_mfma_f32_16x16x32_bf16(Ah1, Bm, acc1, 0, 0, 0); \
      acc1 = __builtin_amdgcn_mfma_f32_16x16x32_bf16(Am1, Bh, acc1, 0, 0, 0); \
      acc1 = __builtin_amdgcn_mfma_f32_16x16x32_bf16(Ah1, Bl, acc1, 0, 0, 0); \
      acc1 = __builtin_amdgcn_mfma_f32_16x16x32_bf16(Al1, Bh, acc1, 0, 0, 0); \
      acc1 = __builtin_amdgcn_mfma_f32_16x16x32_bf16(Am1, Bm, acc1, 0, 0, 0); \
    }

  // phase ph: split cur regs, prefetch ph+1, barrier, MFMA, barrier
  #define DO_PHASE(ph, C0, C1, N0, N1, PRE)                               \
    SPLIT_PHASE(C0, C1);                                                  \
    if (PRE) {                                                            \
      N0 = *(const float4*)&sx[(ph + 1) * 128];                           \
      N1 = *(const float4*)&sx[(ph + 1) * 128 + 4];                       \
    }                                                                     \
    __syncthreads();                                                      \
    MFMA_PHASE(ph);                                                       \
    __syncthreads();

  // prologue
  xa0 = *(const float4*)&sx[0];
  xa1 = *(const float4*)&sx[4];

  DO_PHASE(0, xa0, xa1, xb0, xb1, 1);
  DO_PHASE(1, xb0, xb1, xa0, xa1, 1);
  DO_PHASE(2, xa0, xa1, xb0, xb1, 1);
  DO_PHASE(3, xb0, xb1, xa0, xa1, 1);
  DO_PHASE(4, xa0, xa1, xb0, xb1, 1);
  DO_PHASE(5, xb0, xb1, xa0, xa1, 1);
  DO_PHASE(6, xa0, xa1, xb0, xb1, 1);
  DO_PHASE(7, xb0, xb1, xa0, xa1, 0);   // trailing barrier protects aliasing

  #undef DO_PHASE
  #undef SPLIT_PHASE
  #undef MFMA_PHASE
  #undef PS

  // ---- epilogue LDS aliases the x-stage buffer (all ldsA reads done) ----
  float (*lds_logits)[NCOL + 4] = (float (*)[NCOL + 4])LA;   // 16896 B
  float (*lps)[NEXP] = (float (*)[NEXP])(LA + 16896);        // 2048 B
  float (*lcb)[NEXP] = (float (*)[NEXP])(LA + 18944);        // 2048 B
  float* lspw        = (float*)(LA + 20992);                 // 32 B

  // C-write: D row = 4*(lane>>4)+r, col = lane&15 (m89-verified); wave = ct
  #pragma unroll
  for (int r = 0; r < 4; ++r) {
    lds_logits[4 * fr_s + r][w * 16 + fr_row]      = acc0[r];   // tg0 rows 0..15
    lds_logits[16 + 4 * fr_s + r][w * 16 + fr_row] = acc1[r];   // tg1 rows 16..31
  }
  __syncthreads();

  // ---- epilogue: 4 tokens per wave, lane = expert (identical to r1 K2 math) ----
  float* out_rw  = out;                        // [16384][2]
  float* out_idx = out + 2 * TOKENS;           // [16384][2]
  float* out_rp  = out + 4 * TOKENS + 1;       // [16384][64]

  float ps_acc = 0.0f, sp_acc = 0.0f, c_acc = 0.0f;

  for (int it = 0; it < 4; ++it) {
    const int tl = w * 4 + it;
    const int t  = tok0 + tl;
    const float cl = lds_logits[tl][lane];
    const float nl = lds_logits[tl][NEXP + lane];

    // router_probs = softmax(clean)
    const float m  = wave_max64(cl);
    const float v  = expf(cl - m);
    const float Z  = wave_sum64(v);
    const float rp = v / Z;
    out_rp[(size_t)t * NEXP + lane] = rp;
    ps_acc += rp;

    // noisy logits
    const float ns  = softplus_ref(nl);
    sp_acc += ns;
    const float noi = noise_normal((uint32_t)(t * NEXP + lane));
    const float lgn = __fadd_rn(cl, __fmul_rn(noi, ns));

    const float m2 = wave_max64(lgn);
    const float v2 = expf(lgn - m2);
    const float Z2 = wave_sum64(v2);
    const float p  = v2 / Z2;

    float p1; int i1;
    wave_argmax64(p, lane, p1, i1);
    const float pm = (lane == i1) ? -3.402823466e38f : p;
    float p2; int i2;
    wave_argmax64(pm, lane, p2, i2);

    c_acc += (float)((lane == i1) + (lane == i2));

    if (lane == 0) {
      const float s = p1 + p2;
      out_rw[t * 2 + 0]  = p1 / s;
      out_rw[t * 2 + 1]  = p2 / s;
      out_idx[t * 2 + 0] = (float)i1;
      out_idx[t * 2 + 1] = (float)i2;
    }
  }

  // block-level reduce, then one atomicAdd set per block
  lps[w][lane] = ps_acc;
  lcb[w][lane] = c_acc;
  const float spw = wave_sum64(sp_acc);
  if (lane == 0) lspw[w] = spw;
  __syncthreads();
  if (tid < NEXP) {
    float a = 0.0f, b = 0.0f;
    #pragma unroll
    for (int j = 0; j < 8; ++j) { a += lps[j][tid]; b += lcb[j][tid]; }
    atomicAdd(&g_ps[tid],  a);
    atomicAdd(&g_cnt[tid], b);
  }
  if (tid == 0) {
    float s = 0.0f;
    #pragma unroll
    for (int j = 0; j < 8; ++j) s += lspw[j];
    atomicAdd(&g_spa[0], s);
  }
}

// ---------------- K3: finalize scalars ----------------
__global__ void finalize_kernel(float* __restrict__ out) {
  const int lane = threadIdx.x;
  float term = (g_cnt[lane] / (float)TOKENS) * (g_ps[lane] / (float)TOKENS);
  #pragma unroll
  for (int off = 32; off; off >>= 1) term += __shfl_xor(term, off, 64);
  if (lane == 0) {
    out[4 * TOKENS] = 0.64f * term;   // LOAD_BALANCE_WEIGHT * NUM_EXPERTS
    out[4 * TOKENS + 1 + TOKENS * NEXP] = g_spa[0] / (float)(TOKENS * NEXP);
  }
}

// ---------------- host ----------------
extern "C" void kernel_launch(void* const* d_in, const int* in_sizes, int n_in,
                              void* d_out, int out_size, void* d_ws, size_t ws_size,
                              hipStream_t stream) {
  const float* x  = (const float*)d_in[0];   // f32 [4,4096,1024]
  const float* wg = (const float*)d_in[1];   // f32 [64,1024]
  const float* wn = (const float*)d_in[2];   // f32 [64,1024]
  float* out = (float*)d_out;                // f32, 1114114 elements

  (void)d_ws; (void)ws_size; (void)in_sizes; (void)n_in; (void)out_size;

  wsplit_kernel<<<NTILE * NCH, 64, 0, stream>>>(wg, wn);
  NoisyTopKRouter_57621281243491_kernel<<<NBLK, 512, 0, stream>>>(x, out);
  finalize_kernel<<<1, 64, 0, stream>>>(out);
}